// Round 2
// baseline (1178.052 us; speedup 1.0000x reference)
//
#include <hip/hip_runtime.h>
#include <hip/hip_bf16.h>
#include <math.h>

#define NHEADS 16
#define HD     128
#define CEMB   2048
#define BATCH  4
#define TSEQ   2048

typedef __attribute__((ext_vector_type(8))) short bf16x8;
typedef __attribute__((ext_vector_type(4))) float f32x4;

#define NEGF (-1.0e30f)
#define WIN  2.5e-4f     // fp64 fixup window in score units; 3-term bf16-split err ~2e-5 typ

__device__ inline short f2bf(float x) {
    __hip_bfloat16 h = __float2bfloat16(x);
    return *reinterpret_cast<short*>(&h);
}
__device__ inline void split2(float x, short& hi, short& lo) {
    __hip_bfloat16 h = __float2bfloat16(x);
    float hf = __bfloat162float(h);
    __hip_bfloat16 l = __float2bfloat16(x - hf);
    hi = *reinterpret_cast<short*>(&h);
    lo = *reinterpret_cast<short*>(&l);
}

// Per-CU balance map: CU gets blocks id, id+256, id+512, id+768 (round-robin);
// slots {s,s+4,s+8,s+12} must sum to equal work. QMAP gives each CU 34 units.
__device__ __constant__ int QMAP[16] = {15,14,13,12, 8,9,10,11, 7,6,5,4, 0,1,2,3};

// ---------------- MFMA flash attention with exact-floor scores ----------------
// 1D grid 1024: bh = id&63 (fastest), qblk = QMAP[id>>6]. Block = 4 waves,
// 128 q-rows; wave owns 32 rows (two 16-row sub-tiles). K-tiles of 32.
// MFMA 16x16x32 layouts: A[m=lane&15][k=quad*8+j]; B[k=quad*8+j][n=lane&15];
// C/D row=quad*4+reg, col=lane&15.
// launch_bounds (256,2): unified VGPR+AGPR budget 256/wave. Persistent state
// qhi/qlo (64 VGPR) + oacc (64 AGPR) + prefetch regs (32 VGPR). (256,4)
// spilled (r0: 2.3GB scratch reads). r2: T14 async-stage — prefetch next
// K/V tile into regs during compute, convert+write LDS after read-barrier.
__global__ __launch_bounds__(256, 2)
void attn_mfma(const float* __restrict__ Q, const float* __restrict__ K,
               const float* __restrict__ V, __hip_bfloat16* __restrict__ O)
{
    __shared__ __align__(16) short Khi[32][136];
    __shared__ __align__(16) short Klo[32][136];
    // Vt[hd][k]: 64B rows, group-swizzled: k-group g of row hd stored at
    // position g ^ ((hd>>2)&3). k-order inside groups preserved -> MFMA-legal.
    __shared__ __align__(16) short Vt[128][32];
    __shared__ __align__(16) short Ps[4][32][40];

    const int tid  = threadIdx.x;
    const int wave = tid >> 6;
    const int lane = tid & 63;
    const int quad = lane >> 4;
    const int n    = lane & 15;

    const int id   = blockIdx.x;
    const int bh   = id & 63;
    const int qblk = QMAP[id >> 6];
    const int b    = bh >> 4;
    const int h    = bh & 15;
    const int q0w  = qblk * 128 + wave * 32;

    const size_t inbase = ((size_t)b * TSEQ) * CEMB + (size_t)h * HD;

    const float  scale     = sqrtf(128.0f);
    const double dscale    = (double)scale;
    const float  inv_scale = 1.0f / scale;

    // ---- Q fragments (resident): hi/lo bf16 split ----
    bf16x8 qhi[2][4], qlo[2][4];
    #pragma unroll
    for (int s = 0; s < 2; ++s) {
        #pragma unroll
        for (int ks = 0; ks < 4; ++ks) {
            const float* qp = Q + inbase + (size_t)(q0w + 16 * s + n) * CEMB + 32 * ks + 8 * quad;
            float4 f0 = *(const float4*)qp;
            float4 f1 = *(const float4*)(qp + 4);
            float fv[8] = {f0.x, f0.y, f0.z, f0.w, f1.x, f1.y, f1.z, f1.w};
            bf16x8 h8, l8;
            #pragma unroll
            for (int j = 0; j < 8; ++j) {
                short hj, lj;
                split2(fv[j], hj, lj);
                h8[j] = hj; l8[j] = lj;
            }
            qhi[s][ks] = h8;
            qlo[s][ks] = l8;
        }
    }

    f32x4 oacc[2][8];
    #pragma unroll
    for (int s = 0; s < 2; ++s)
        #pragma unroll
        for (int nt = 0; nt < 8; ++nt)
            oacc[s][nt] = (f32x4){0.f, 0.f, 0.f, 0.f};

    float m_r[2][4], l_r[2][4];
    #pragma unroll
    for (int s = 0; s < 2; ++s)
        #pragma unroll
        for (int reg = 0; reg < 4; ++reg) { m_r[s][reg] = NEGF; l_r[s][reg] = 0.f; }

    const int nkt = 4 * (qblk + 1);

    // ---- prefetch registers (stay in regs: statically indexed) ----
    float4 kreg[4], vreg[4];

    auto issue_loads = [&](int ktn) {
        #pragma unroll
        for (int it = 0; it < 4; ++it) {
            int idx = tid + 256 * it;      // 0..1023
            int r   = idx >> 5;            // 0..31
            int c4  = idx & 31;            // float4 within row
            size_t off = inbase + (size_t)(ktn * 32 + r) * CEMB + 4 * c4;
            kreg[it] = *(const float4*)(K + off);
            vreg[it] = *(const float4*)(V + off);
        }
    };
    auto write_lds = [&]() {
        #pragma unroll
        for (int it = 0; it < 4; ++it) {
            int idx = tid + 256 * it;
            int r   = idx >> 5;
            int c4  = idx & 31;
            float4 kv = kreg[it];
            float4 vv = vreg[it];
            short4 khi4, klo4;
            split2(kv.x, khi4.x, klo4.x); split2(kv.y, khi4.y, klo4.y);
            split2(kv.z, khi4.z, klo4.z); split2(kv.w, khi4.w, klo4.w);
            *(short4*)&Khi[r][4 * c4] = khi4;
            *(short4*)&Klo[r][4 * c4] = klo4;
            int pos = 8 * ((r >> 3) ^ (c4 & 3)) + (r & 7);
            Vt[4 * c4 + 0][pos] = f2bf(vv.x);
            Vt[4 * c4 + 1][pos] = f2bf(vv.y);
            Vt[4 * c4 + 2][pos] = f2bf(vv.z);
            Vt[4 * c4 + 3][pos] = f2bf(vv.w);
        }
    };

    // ---- prologue: stage tile 0 ----
    issue_loads(0);
    write_lds();

    for (int kt = 0; kt < nkt; ++kt) {
        const int k0 = kt * 32;
        __syncthreads();                    // staged LDS visible to all
        const bool havenext = (kt + 1 < nkt);
        if (havenext) issue_loads(kt + 1);  // in flight during compute

        if (k0 <= q0w + 31) {   // causal: wave has live rows in this K-tile
            // ---- S = Q·K^T via 3-term bf16-split MFMA ----
            f32x4 sacc[2][2];
            #pragma unroll
            for (int s = 0; s < 2; ++s)
                #pragma unroll
                for (int nt = 0; nt < 2; ++nt)
                    sacc[s][nt] = (f32x4){0.f, 0.f, 0.f, 0.f};

            #pragma unroll
            for (int ks = 0; ks < 4; ++ks) {
                #pragma unroll
                for (int nt = 0; nt < 2; ++nt) {
                    bf16x8 khf = *(const bf16x8*)&Khi[16 * nt + n][32 * ks + 8 * quad];
                    bf16x8 klf = *(const bf16x8*)&Klo[16 * nt + n][32 * ks + 8 * quad];
                    #pragma unroll
                    for (int s = 0; s < 2; ++s) {
                        sacc[s][nt] = __builtin_amdgcn_mfma_f32_16x16x32_bf16(qhi[s][ks], khf, sacc[s][nt], 0, 0, 0);
                        sacc[s][nt] = __builtin_amdgcn_mfma_f32_16x16x32_bf16(qhi[s][ks], klf, sacc[s][nt], 0, 0, 0);
                        sacc[s][nt] = __builtin_amdgcn_mfma_f32_16x16x32_bf16(qlo[s][ks], khf, sacc[s][nt], 0, 0, 0);
                    }
                }
            }

            // ---- floor + fp64 boundary fixup + online softmax, write P ----
            #pragma unroll
            for (int s = 0; s < 2; ++s) {
                float sc[2][4];
                #pragma unroll
                for (int nt = 0; nt < 2; ++nt) {
                    #pragma unroll
                    for (int reg = 0; reg < 4; ++reg) {
                        int qrow = q0w + 16 * s + 4 * quad + reg;
                        int kcol = k0 + 16 * nt + n;
                        if (kcol > qrow) { sc[nt][reg] = NEGF; continue; }
                        float sv = sacc[s][nt][reg] * inv_scale;
                        float f  = floorf(sv);
                        float fr = sv - f;
                        if (fr < WIN || fr > 1.0f - WIN) {
                            // vectorized fp64 re-check: 4 independent chains
                            const float4* qp4 = (const float4*)(Q + inbase + (size_t)qrow * CEMB);
                            const float4* kp4 = (const float4*)(K + inbase + (size_t)kcol * CEMB);
                            double d0 = 0.0, d1 = 0.0, d2 = 0.0, d3 = 0.0;
                            #pragma unroll 4
                            for (int kk = 0; kk < HD / 4; ++kk) {
                                float4 aq = qp4[kk];
                                float4 bk = kp4[kk];
                                d0 += (double)aq.x * bk.x;
                                d1 += (double)aq.y * bk.y;
                                d2 += (double)aq.z * bk.z;
                                d3 += (double)aq.w * bk.w;
                            }
                            f = (float)floor(((d0 + d1) + (d2 + d3)) / dscale);
                        }
                        sc[nt][reg] = f;
                    }
                }
                float alphaL[4];
                #pragma unroll
                for (int reg = 0; reg < 4; ++reg) {
                    float tm = fmaxf(sc[0][reg], sc[1][reg]);
                    tm = fmaxf(tm, __shfl_xor(tm, 1));
                    tm = fmaxf(tm, __shfl_xor(tm, 2));
                    tm = fmaxf(tm, __shfl_xor(tm, 4));
                    tm = fmaxf(tm, __shfl_xor(tm, 8));
                    float mo = m_r[s][reg];
                    float mn = fmaxf(mo, tm);
                    float al = (mo < -1e29f) ? 0.0f : expf(mo - mn);
                    float p0 = (sc[0][reg] < -1e29f) ? 0.0f : expf(sc[0][reg] - mn);
                    float p1 = (sc[1][reg] < -1e29f) ? 0.0f : expf(sc[1][reg] - mn);
                    float ps = p0 + p1;
                    ps += __shfl_xor(ps, 1);
                    ps += __shfl_xor(ps, 2);
                    ps += __shfl_xor(ps, 4);
                    ps += __shfl_xor(ps, 8);
                    l_r[s][reg] = l_r[s][reg] * al + ps;
                    m_r[s][reg] = mn;
                    alphaL[reg] = al;
                    Ps[wave][16 * s + 4 * quad + reg][n]      = f2bf(p0);
                    Ps[wave][16 * s + 4 * quad + reg][16 + n] = f2bf(p1);
                }
                #pragma unroll
                for (int ntv = 0; ntv < 8; ++ntv) {
                    #pragma unroll
                    for (int reg = 0; reg < 4; ++reg)
                        oacc[s][ntv][reg] *= alphaL[reg];
                }
            }

            // ---- O += P·V: A-frag from Ps, B-frag b128 from swizzled Vt ----
            bf16x8 pfa[2];
            pfa[0] = *(const bf16x8*)&Ps[wave][n][8 * quad];
            pfa[1] = *(const bf16x8*)&Ps[wave][16 + n][8 * quad];
            #pragma unroll
            for (int ntv = 0; ntv < 8; ++ntv) {
                bf16x8 vf = *(const bf16x8*)&Vt[16 * ntv + n][8 * (quad ^ (n >> 2))];
                oacc[0][ntv] = __builtin_amdgcn_mfma_f32_16x16x32_bf16(pfa[0], vf, oacc[0][ntv], 0, 0, 0);
                oacc[1][ntv] = __builtin_amdgcn_mfma_f32_16x16x32_bf16(pfa[1], vf, oacc[1][ntv], 0, 0, 0);
            }
        }

        __syncthreads();                    // all waves done reading LDS
        if (havenext) write_lds();          // vmcnt wait + convert + ds_write
    }

    // ---- normalize + write bf16 merged-head layout [b, t, h*128 + c] ----
    #pragma unroll
    for (int s = 0; s < 2; ++s) {
        #pragma unroll
        for (int reg = 0; reg < 4; ++reg) {
            float inv = 1.0f / l_r[s][reg];
            int qrow = q0w + 16 * s + 4 * quad + reg;
            __hip_bfloat16* op = O + ((size_t)b * TSEQ + qrow) * CEMB + (size_t)h * HD;
            #pragma unroll
            for (int ntv = 0; ntv < 8; ++ntv)
                op[16 * ntv + n] = __float2bfloat16(oacc[s][ntv][reg] * inv);
        }
    }
}

// ---------------- projection: out = X(bf16) @ W^T + bias, MFMA ----------------
// Tile 128x128, K-slab 32. Block 256 = 4 waves in 2x2; wave does 64x64 via
// 4x4 sub-tiles of 16x16x32 (one MFMA consumes the whole slab).
__global__ __launch_bounds__(256)
void proj_mfma(const __hip_bfloat16* __restrict__ X, const float* __restrict__ W,
               const float* __restrict__ bias, float* __restrict__ out)
{
    __shared__ __align__(16) short Xs[128][40];
    __shared__ __align__(16) short Ws[128][40];

    const int tid  = threadIdx.x;
    const int wave = tid >> 6;
    const int lane = tid & 63;
    const int quad = lane >> 4;
    const int n    = lane & 15;
    const int wm   = wave >> 1;
    const int wn   = wave & 1;

    const int m0 = blockIdx.y * 128;
    const int n0 = blockIdx.x * 128;

    f32x4 acc[4][4];
    #pragma unroll
    for (int i = 0; i < 4; ++i)
        #pragma unroll
        for (int j = 0; j < 4; ++j)
            acc[i][j] = (f32x4){0.f, 0.f, 0.f, 0.f};

    for (int k0 = 0; k0 < CEMB; k0 += 32) {
        __syncthreads();
        // X: bf16 direct, 128x32 = 512 16B-chunks
        #pragma unroll
        for (int ii = 0; ii < 2; ++ii) {
            int idx = tid + 256 * ii;          // 0..511
            int row = idx >> 2;                // 0..127
            int c   = idx & 3;                 // 16B group
            *(bf16x8*)&Xs[row][8 * c] =
                *(const bf16x8*)(X + (size_t)(m0 + row) * CEMB + k0 + 8 * c);
        }
        // W: fp32 -> bf16, 128x32 = 1024 float4
        #pragma unroll
        for (int ii = 0; ii < 4; ++ii) {
            int idx = tid + 256 * ii;          // 0..1023
            int row = idx >> 3;                // 0..127
            int c4  = idx & 7;
            float4 wv = *(const float4*)(W + (size_t)(n0 + row) * CEMB + k0 + 4 * c4);
            short4 w4;
            w4.x = f2bf(wv.x); w4.y = f2bf(wv.y); w4.z = f2bf(wv.z); w4.w = f2bf(wv.w);
            *(short4*)&Ws[row][4 * c4] = w4;
        }
        __syncthreads();

        bf16x8 a[4], bb[4];
        #pragma unroll
        for (int i = 0; i < 4; ++i)
            a[i] = *(const bf16x8*)&Xs[64 * wm + 16 * i + n][8 * quad];
        #pragma unroll
        for (int j = 0; j < 4; ++j)
            bb[j] = *(const bf16x8*)&Ws[64 * wn + 16 * j + n][8 * quad];
        #pragma unroll
        for (int i = 0; i < 4; ++i)
            #pragma unroll
            for (int j = 0; j < 4; ++j)
                acc[i][j] = __builtin_amdgcn_mfma_f32_16x16x32_bf16(a[i], bb[j], acc[i][j], 0, 0, 0);
    }

    #pragma unroll
    for (int j = 0; j < 4; ++j) {
        int col = n0 + 64 * wn + 16 * j + n;
        float bj = bias[col];
        #pragma unroll
        for (int i = 0; i < 4; ++i) {
            #pragma unroll
            for (int reg = 0; reg < 4; ++reg) {
                int row = m0 + 64 * wm + 16 * i + 4 * quad + reg;
                out[(size_t)row * CEMB + col] = acc[i][j][reg] + bj;
            }
        }
    }
}

extern "C" void kernel_launch(void* const* d_in, const int* in_sizes, int n_in,
                              void* d_out, int out_size, void* d_ws, size_t ws_size,
                              hipStream_t stream)
{
    // setup_inputs order: v, k, q, W_out, b_out
    const float* v    = (const float*)d_in[0];
    const float* k    = (const float*)d_in[1];
    const float* q    = (const float*)d_in[2];
    const float* W    = (const float*)d_in[3];
    const float* bias = (const float*)d_in[4];

    __hip_bfloat16* attn = (__hip_bfloat16*)d_ws;   // B*T*C bf16 = 32 MiB scratch
    float* out = (float*)d_out;

    attn_mfma<<<dim3(1024), 256, 0, stream>>>(q, k, v, attn);

    dim3 pgrid(CEMB / 128, (BATCH * TSEQ) / 128);   // (16, 64)
    proj_mfma<<<pgrid, 256, 0, stream>>>(attn, W, bias, out);
}

// Round 3
// 1091.597 us; speedup vs baseline: 1.0792x; 1.0792x over previous
//
#include <hip/hip_runtime.h>
#include <hip/hip_bf16.h>
#include <math.h>

#define NHEADS 16
#define HD     128
#define CEMB   2048
#define BATCH  4
#define TSEQ   2048

typedef __attribute__((ext_vector_type(8))) short bf16x8;
typedef __attribute__((ext_vector_type(4))) float f32x4;

#define NEGF (-1.0e30f)
#define WIN  2.5e-4f     // fp64 fixup window in score units; 3-term bf16-split err ~2e-5 typ

__device__ inline short f2bf(float x) {
    __hip_bfloat16 h = __float2bfloat16(x);
    return *reinterpret_cast<short*>(&h);
}
__device__ inline void split2(float x, short& hi, short& lo) {
    __hip_bfloat16 h = __float2bfloat16(x);
    float hf = __bfloat162float(h);
    __hip_bfloat16 l = __float2bfloat16(x - hf);
    hi = *reinterpret_cast<short*>(&h);
    lo = *reinterpret_cast<short*>(&l);
}

// async global->LDS DMA, 16B per lane. LDS dest must be wave-uniform base;
// lane l lands at base + 16*l (linear). Global src is per-lane.
__device__ inline void gll16(const float* g, float* lds_linear) {
    __builtin_amdgcn_global_load_lds(
        (const __attribute__((address_space(1))) unsigned int*)g,
        (__attribute__((address_space(3))) unsigned int*)lds_linear, 16, 0, 0);
}

// Per-CU balance map: CU gets blocks id, id+256, id+512, id+768 (round-robin);
// slots {s,s+4,s+8,s+12} must sum to equal work. QMAP gives each CU 34 units.
__device__ __constant__ int QMAP[16] = {15,14,13,12, 8,9,10,11, 7,6,5,4, 0,1,2,3};

// ---------------- MFMA flash attention with exact-floor scores ----------------
// 1D grid 1024: bh = id&63 (fastest), qblk = QMAP[id>>6]. Block = 4 waves,
// 128 q-rows; wave owns 32 rows (two 16-row sub-tiles). K-tiles of 32.
// MFMA 16x16x32 layouts: A[m=lane&15][k=quad*8+j]; B[k=quad*8+j][n=lane&15];
// C/D row=quad*4+reg, col=lane&15.
// launch_bounds (256,2): persistent state qhi/qlo (64 VGPR) + oacc (64 AGPR).
// r0: (256,4) spilled -> 2.3GB scratch. r2: reg-staged prefetch (+32 VGPR)
// spilled -> regression. r3: global_load_lds DMA prefetch of raw fp32 K/V
// into linear LDS (zero reg cost), convert LDS->LDS after compute barrier.
__global__ __launch_bounds__(256, 2)
void attn_mfma(const float* __restrict__ Q, const float* __restrict__ K,
               const float* __restrict__ V, __hip_bfloat16* __restrict__ O)
{
    __shared__ __align__(16) short Khi[32][136];
    __shared__ __align__(16) short Klo[32][136];
    // Vt[hd][k]: 64B rows, group-swizzled: k-group g of row hd stored at
    // position g ^ ((hd>>2)&3). k-order inside groups preserved -> MFMA-legal.
    __shared__ __align__(16) short Vt[128][32];
    __shared__ __align__(16) short Ps[4][32][40];
    // raw fp32 staging for tile t+1 (DMA target; must be LINEAR, no pad)
    __shared__ __align__(16) float Kraw[32 * 128];
    __shared__ __align__(16) float Vraw[32 * 128];

    const int tid  = threadIdx.x;
    const int wave = tid >> 6;
    const int lane = tid & 63;
    const int quad = lane >> 4;
    const int n    = lane & 15;

    const int id   = blockIdx.x;
    const int bh   = id & 63;
    const int qblk = QMAP[id >> 6];
    const int b    = bh >> 4;
    const int h    = bh & 15;
    const int q0w  = qblk * 128 + wave * 32;

    const size_t inbase = ((size_t)b * TSEQ) * CEMB + (size_t)h * HD;

    const float  scale     = sqrtf(128.0f);
    const double dscale    = (double)scale;
    const float  inv_scale = 1.0f / scale;

    // issue DMA for tile ktn: wave w loads 1KB chunks 4w..4w+3 of K and V.
    // chunk c = rows [2c, 2c+1]; lane l -> row 2c + (l>>5), 16B at float 4*(l&31).
    auto issue_gll = [&](int ktn) {
        #pragma unroll
        for (int c = 0; c < 4; ++c) {
            int chunk = 4 * wave + c;
            int row   = 2 * chunk + (lane >> 5);
            int colf  = 4 * (lane & 31);
            size_t off = inbase + (size_t)(ktn * 32 + row) * CEMB + colf;
            gll16(K + off, Kraw + chunk * 256);
            gll16(V + off, Vraw + chunk * 256);
        }
    };
    // convert raw fp32 tile (LDS) -> Khi/Klo split + Vt bf16 transposed/swizzled
    auto convert_tile = [&]() {
        #pragma unroll
        for (int it = 0; it < 4; ++it) {
            int idx = tid + 256 * it;      // 0..1023
            int r   = idx >> 5;            // 0..31
            int c4  = idx & 31;            // float4 within row
            float4 kv = *(const float4*)&Kraw[r * 128 + 4 * c4];
            float4 vv = *(const float4*)&Vraw[r * 128 + 4 * c4];
            short4 khi4, klo4;
            split2(kv.x, khi4.x, klo4.x); split2(kv.y, khi4.y, klo4.y);
            split2(kv.z, khi4.z, klo4.z); split2(kv.w, khi4.w, klo4.w);
            *(short4*)&Khi[r][4 * c4] = khi4;
            *(short4*)&Klo[r][4 * c4] = klo4;
            int pos = 8 * ((r >> 3) ^ (c4 & 3)) + (r & 7);
            Vt[4 * c4 + 0][pos] = f2bf(vv.x);
            Vt[4 * c4 + 1][pos] = f2bf(vv.y);
            Vt[4 * c4 + 2][pos] = f2bf(vv.z);
            Vt[4 * c4 + 3][pos] = f2bf(vv.w);
        }
    };

    // ---- prologue: start tile-0 DMA, then Q preload overlaps it ----
    issue_gll(0);

    bf16x8 qhi[2][4], qlo[2][4];
    #pragma unroll
    for (int s = 0; s < 2; ++s) {
        #pragma unroll
        for (int ks = 0; ks < 4; ++ks) {
            const float* qp = Q + inbase + (size_t)(q0w + 16 * s + n) * CEMB + 32 * ks + 8 * quad;
            float4 f0 = *(const float4*)qp;
            float4 f1 = *(const float4*)(qp + 4);
            float fv[8] = {f0.x, f0.y, f0.z, f0.w, f1.x, f1.y, f1.z, f1.w};
            bf16x8 h8, l8;
            #pragma unroll
            for (int j = 0; j < 8; ++j) {
                short hj, lj;
                split2(fv[j], hj, lj);
                h8[j] = hj; l8[j] = lj;
            }
            qhi[s][ks] = h8;
            qlo[s][ks] = l8;
        }
    }

    f32x4 oacc[2][8];
    #pragma unroll
    for (int s = 0; s < 2; ++s)
        #pragma unroll
        for (int nt = 0; nt < 8; ++nt)
            oacc[s][nt] = (f32x4){0.f, 0.f, 0.f, 0.f};

    float m_r[2][4], l_r[2][4];
    #pragma unroll
    for (int s = 0; s < 2; ++s)
        #pragma unroll
        for (int reg = 0; reg < 4; ++reg) { m_r[s][reg] = NEGF; l_r[s][reg] = 0.f; }

    const int nkt = 4 * (qblk + 1);

    __syncthreads();      // drains vmcnt: tile-0 raw landed; visible to all
    convert_tile();

    for (int kt = 0; kt < nkt; ++kt) {
        const int k0 = kt * 32;
        __syncthreads();                    // staged tile kt visible; raw buffer free
        const bool havenext = (kt + 1 < nkt);
        if (havenext) issue_gll(kt + 1);    // DMA in flight during compute

        if (k0 <= q0w + 31) {   // causal: wave has live rows in this K-tile
            // ---- S = Q·K^T via 3-term bf16-split MFMA ----
            f32x4 sacc[2][2];
            #pragma unroll
            for (int s = 0; s < 2; ++s)
                #pragma unroll
                for (int nt = 0; nt < 2; ++nt)
                    sacc[s][nt] = (f32x4){0.f, 0.f, 0.f, 0.f};

            __builtin_amdgcn_s_setprio(1);
            #pragma unroll
            for (int ks = 0; ks < 4; ++ks) {
                #pragma unroll
                for (int nt = 0; nt < 2; ++nt) {
                    bf16x8 khf = *(const bf16x8*)&Khi[16 * nt + n][32 * ks + 8 * quad];
                    bf16x8 klf = *(const bf16x8*)&Klo[16 * nt + n][32 * ks + 8 * quad];
                    #pragma unroll
                    for (int s = 0; s < 2; ++s) {
                        sacc[s][nt] = __builtin_amdgcn_mfma_f32_16x16x32_bf16(qhi[s][ks], khf, sacc[s][nt], 0, 0, 0);
                        sacc[s][nt] = __builtin_amdgcn_mfma_f32_16x16x32_bf16(qhi[s][ks], klf, sacc[s][nt], 0, 0, 0);
                        sacc[s][nt] = __builtin_amdgcn_mfma_f32_16x16x32_bf16(qlo[s][ks], khf, sacc[s][nt], 0, 0, 0);
                    }
                }
            }
            __builtin_amdgcn_s_setprio(0);

            // ---- floor + fp64 boundary fixup + online softmax, write P ----
            #pragma unroll
            for (int s = 0; s < 2; ++s) {
                float sc[2][4];
                #pragma unroll
                for (int nt = 0; nt < 2; ++nt) {
                    #pragma unroll
                    for (int reg = 0; reg < 4; ++reg) {
                        int qrow = q0w + 16 * s + 4 * quad + reg;
                        int kcol = k0 + 16 * nt + n;
                        if (kcol > qrow) { sc[nt][reg] = NEGF; continue; }
                        float sv = sacc[s][nt][reg] * inv_scale;
                        float f  = floorf(sv);
                        float fr = sv - f;
                        if (fr < WIN || fr > 1.0f - WIN) {
                            // vectorized fp64 re-check: 4 independent chains
                            const float4* qp4 = (const float4*)(Q + inbase + (size_t)qrow * CEMB);
                            const float4* kp4 = (const float4*)(K + inbase + (size_t)kcol * CEMB);
                            double d0 = 0.0, d1 = 0.0, d2 = 0.0, d3 = 0.0;
                            #pragma unroll 2
                            for (int kk = 0; kk < HD / 4; ++kk) {
                                float4 aq = qp4[kk];
                                float4 bk = kp4[kk];
                                d0 += (double)aq.x * bk.x;
                                d1 += (double)aq.y * bk.y;
                                d2 += (double)aq.z * bk.z;
                                d3 += (double)aq.w * bk.w;
                            }
                            f = (float)floor(((d0 + d1) + (d2 + d3)) / dscale);
                        }
                        sc[nt][reg] = f;
                    }
                }
                float alphaL[4];
                #pragma unroll
                for (int reg = 0; reg < 4; ++reg) {
                    float tm = fmaxf(sc[0][reg], sc[1][reg]);
                    tm = fmaxf(tm, __shfl_xor(tm, 1));
                    tm = fmaxf(tm, __shfl_xor(tm, 2));
                    tm = fmaxf(tm, __shfl_xor(tm, 4));
                    tm = fmaxf(tm, __shfl_xor(tm, 8));
                    float mo = m_r[s][reg];
                    float mn = fmaxf(mo, tm);
                    float al = (mo < -1e29f) ? 0.0f : expf(mo - mn);
                    float p0 = (sc[0][reg] < -1e29f) ? 0.0f : expf(sc[0][reg] - mn);
                    float p1 = (sc[1][reg] < -1e29f) ? 0.0f : expf(sc[1][reg] - mn);
                    float ps = p0 + p1;
                    ps += __shfl_xor(ps, 1);
                    ps += __shfl_xor(ps, 2);
                    ps += __shfl_xor(ps, 4);
                    ps += __shfl_xor(ps, 8);
                    l_r[s][reg] = l_r[s][reg] * al + ps;
                    m_r[s][reg] = mn;
                    alphaL[reg] = al;
                    Ps[wave][16 * s + 4 * quad + reg][n]      = f2bf(p0);
                    Ps[wave][16 * s + 4 * quad + reg][16 + n] = f2bf(p1);
                }
                #pragma unroll
                for (int ntv = 0; ntv < 8; ++ntv) {
                    #pragma unroll
                    for (int reg = 0; reg < 4; ++reg)
                        oacc[s][ntv][reg] *= alphaL[reg];
                }
            }

            // ---- O += P·V: A-frag from Ps, B-frag b128 from swizzled Vt ----
            bf16x8 pfa[2];
            pfa[0] = *(const bf16x8*)&Ps[wave][n][8 * quad];
            pfa[1] = *(const bf16x8*)&Ps[wave][16 + n][8 * quad];
            __builtin_amdgcn_s_setprio(1);
            #pragma unroll
            for (int ntv = 0; ntv < 8; ++ntv) {
                bf16x8 vf = *(const bf16x8*)&Vt[16 * ntv + n][8 * (quad ^ (n >> 2))];
                oacc[0][ntv] = __builtin_amdgcn_mfma_f32_16x16x32_bf16(pfa[0], vf, oacc[0][ntv], 0, 0, 0);
                oacc[1][ntv] = __builtin_amdgcn_mfma_f32_16x16x32_bf16(pfa[1], vf, oacc[1][ntv], 0, 0, 0);
            }
            __builtin_amdgcn_s_setprio(0);
        }

        __syncthreads();                    // all waves done with staged tile;
                                            // implicit vmcnt(0) drain -> raw t+1 landed
        if (havenext) convert_tile();
    }

    // ---- normalize + write bf16 merged-head layout [b, t, h*128 + c] ----
    #pragma unroll
    for (int s = 0; s < 2; ++s) {
        #pragma unroll
        for (int reg = 0; reg < 4; ++reg) {
            float inv = 1.0f / l_r[s][reg];
            int qrow = q0w + 16 * s + 4 * quad + reg;
            __hip_bfloat16* op = O + ((size_t)b * TSEQ + qrow) * CEMB + (size_t)h * HD;
            #pragma unroll
            for (int ntv = 0; ntv < 8; ++ntv)
                op[16 * ntv + n] = __float2bfloat16(oacc[s][ntv][reg] * inv);
        }
    }
}

// ---------------- projection: out = X(bf16) @ W^T + bias, MFMA ----------------
// Tile 128x128, K-slab 32. Block 256 = 4 waves in 2x2; wave does 64x64 via
// 4x4 sub-tiles of 16x16x32 (one MFMA consumes the whole slab).
__global__ __launch_bounds__(256)
void proj_mfma(const __hip_bfloat16* __restrict__ X, const float* __restrict__ W,
               const float* __restrict__ bias, float* __restrict__ out)
{
    __shared__ __align__(16) short Xs[128][40];
    __shared__ __align__(16) short Ws[128][40];

    const int tid  = threadIdx.x;
    const int wave = tid >> 6;
    const int lane = tid & 63;
    const int quad = lane >> 4;
    const int n    = lane & 15;
    const int wm   = wave >> 1;
    const int wn   = wave & 1;

    const int m0 = blockIdx.y * 128;
    const int n0 = blockIdx.x * 128;

    f32x4 acc[4][4];
    #pragma unroll
    for (int i = 0; i < 4; ++i)
        #pragma unroll
        for (int j = 0; j < 4; ++j)
            acc[i][j] = (f32x4){0.f, 0.f, 0.f, 0.f};

    for (int k0 = 0; k0 < CEMB; k0 += 32) {
        __syncthreads();
        // X: bf16 direct, 128x32 = 512 16B-chunks
        #pragma unroll
        for (int ii = 0; ii < 2; ++ii) {
            int idx = tid + 256 * ii;          // 0..511
            int row = idx >> 2;                // 0..127
            int c   = idx & 3;                 // 16B group
            *(bf16x8*)&Xs[row][8 * c] =
                *(const bf16x8*)(X + (size_t)(m0 + row) * CEMB + k0 + 8 * c);
        }
        // W: fp32 -> bf16, 128x32 = 1024 float4
        #pragma unroll
        for (int ii = 0; ii < 4; ++ii) {
            int idx = tid + 256 * ii;          // 0..1023
            int row = idx >> 3;                // 0..127
            int c4  = idx & 7;
            float4 wv = *(const float4*)(W + (size_t)(n0 + row) * CEMB + k0 + 4 * c4);
            short4 w4;
            w4.x = f2bf(wv.x); w4.y = f2bf(wv.y); w4.z = f2bf(wv.z); w4.w = f2bf(wv.w);
            *(short4*)&Ws[row][4 * c4] = w4;
        }
        __syncthreads();

        bf16x8 a[4], bb[4];
        #pragma unroll
        for (int i = 0; i < 4; ++i)
            a[i] = *(const bf16x8*)&Xs[64 * wm + 16 * i + n][8 * quad];
        #pragma unroll
        for (int j = 0; j < 4; ++j)
            bb[j] = *(const bf16x8*)&Ws[64 * wn + 16 * j + n][8 * quad];
        #pragma unroll
        for (int i = 0; i < 4; ++i)
            #pragma unroll
            for (int j = 0; j < 4; ++j)
                acc[i][j] = __builtin_amdgcn_mfma_f32_16x16x32_bf16(a[i], bb[j], acc[i][j], 0, 0, 0);
    }

    #pragma unroll
    for (int j = 0; j < 4; ++j) {
        int col = n0 + 64 * wn + 16 * j + n;
        float bj = bias[col];
        #pragma unroll
        for (int i = 0; i < 4; ++i) {
            #pragma unroll
            for (int reg = 0; reg < 4; ++reg) {
                int row = m0 + 64 * wm + 16 * i + 4 * quad + reg;
                out[(size_t)row * CEMB + col] = acc[i][j][reg] + bj;
            }
        }
    }
}

extern "C" void kernel_launch(void* const* d_in, const int* in_sizes, int n_in,
                              void* d_out, int out_size, void* d_ws, size_t ws_size,
                              hipStream_t stream)
{
    // setup_inputs order: v, k, q, W_out, b_out
    const float* v    = (const float*)d_in[0];
    const float* k    = (const float*)d_in[1];
    const float* q    = (const float*)d_in[2];
    const float* W    = (const float*)d_in[3];
    const float* bias = (const float*)d_in[4];

    __hip_bfloat16* attn = (__hip_bfloat16*)d_ws;   // B*T*C bf16 = 32 MiB scratch
    float* out = (float*)d_out;

    attn_mfma<<<dim3(1024), 256, 0, stream>>>(q, k, v, attn);

    dim3 pgrid(CEMB / 128, (BATCH * TSEQ) / 128);   // (16, 64)
    proj_mfma<<<pgrid, 256, 0, stream>>>(attn, W, bias, out);
}

// Round 5
// 705.439 us; speedup vs baseline: 1.6700x; 1.5474x over previous
//
#include <hip/hip_runtime.h>
#include <hip/hip_bf16.h>
#include <math.h>

#define NHEADS 16
#define HD     128
#define CEMB   2048
#define BATCH  4
#define TSEQ   2048

typedef __attribute__((ext_vector_type(8))) short bf16x8;
typedef __attribute__((ext_vector_type(4))) float f32x4;

#define NEGF (-1.0e30f)
// fp64 fixup window in score units. r4: 4-term bf16-split MFMA (adds qlo*klo)
// leaves only f32 accumulation error (~5e-6 worst in score units) -> WIN can
// shrink 2.5e-4 -> 4e-5, cutting wave-wide fixup triggers ~6x.
#define WIN  4.0e-5f

__device__ inline short f2bf(float x) {
    __hip_bfloat16 h = __float2bfloat16(x);
    return *reinterpret_cast<short*>(&h);
}
__device__ inline void split2(float x, short& hi, short& lo) {
    __hip_bfloat16 h = __float2bfloat16(x);
    float hf = __bfloat162float(h);
    __hip_bfloat16 l = __float2bfloat16(x - hf);
    hi = *reinterpret_cast<short*>(&h);
    lo = *reinterpret_cast<short*>(&l);
}

// Per-CU balance map: CU gets blocks id, id+256, id+512, id+768 (round-robin);
// slots {s,s+4,s+8,s+12} must sum to equal work. QMAP gives each CU 34 units.
__device__ __constant__ int QMAP[16] = {15,14,13,12, 8,9,10,11, 7,6,5,4, 0,1,2,3};

// ---------------- MFMA flash attention with exact-floor scores ----------------
// 1D grid 1024: bh = id&63 (fastest), qblk = QMAP[id>>6]. Block = 4 waves,
// 128 q-rows; wave owns 32 rows (two 16-row sub-tiles). K-tiles of 32.
// MFMA 16x16x32 layouts: A[m=lane&15][k=quad*8+j]; B[k=quad*8+j][n=lane&15];
// C/D row=quad*4+reg, col=lane&15.
// launch_bounds (256,2): persistent qhi/qlo (64 VGPR) + oacc (64 AGPR).
// History: r0 (256,4) spilled -> 2.3GB scratch. r2 reg-prefetch spilled.
// r3 DMA+LDS-convert: latency hidden but serial convert pass cost more than
// it saved. r4: back to r1 sync staging; attack VALU instead:
//   - __expf everywhere (args are integers <= 0; exp(-1e30)=0 kills guards)
//   - 4-term split MFMA + WIN 4e-5 (fixup rate ~6x down)
//   - defer-rescale: skip oacc*alpha when all alphas == 1 (T13)
// r5: resubmit of r4 (container infra failure, no signal).
__global__ __launch_bounds__(256, 2)
void attn_mfma(const float* __restrict__ Q, const float* __restrict__ K,
               const float* __restrict__ V, __hip_bfloat16* __restrict__ O)
{
    __shared__ __align__(16) short Khi[32][136];
    __shared__ __align__(16) short Klo[32][136];
    // Vt[hd][k]: 64B rows, group-swizzled: k-group g of row hd stored at
    // position g ^ ((hd>>2)&3). k-order inside groups preserved -> MFMA-legal.
    __shared__ __align__(16) short Vt[128][32];
    __shared__ __align__(16) short Ps[4][32][40];

    const int tid  = threadIdx.x;
    const int wave = tid >> 6;
    const int lane = tid & 63;
    const int quad = lane >> 4;
    const int n    = lane & 15;

    const int id   = blockIdx.x;
    const int bh   = id & 63;
    const int qblk = QMAP[id >> 6];
    const int b    = bh >> 4;
    const int h    = bh & 15;
    const int q0w  = qblk * 128 + wave * 32;

    const size_t inbase = ((size_t)b * TSEQ) * CEMB + (size_t)h * HD;

    const float  scale     = sqrtf(128.0f);
    const double dscale    = (double)scale;
    const float  inv_scale = 1.0f / scale;

    // ---- Q fragments (resident): hi/lo bf16 split ----
    bf16x8 qhi[2][4], qlo[2][4];
    #pragma unroll
    for (int s = 0; s < 2; ++s) {
        #pragma unroll
        for (int ks = 0; ks < 4; ++ks) {
            const float* qp = Q + inbase + (size_t)(q0w + 16 * s + n) * CEMB + 32 * ks + 8 * quad;
            float4 f0 = *(const float4*)qp;
            float4 f1 = *(const float4*)(qp + 4);
            float fv[8] = {f0.x, f0.y, f0.z, f0.w, f1.x, f1.y, f1.z, f1.w};
            bf16x8 h8, l8;
            #pragma unroll
            for (int j = 0; j < 8; ++j) {
                short hj, lj;
                split2(fv[j], hj, lj);
                h8[j] = hj; l8[j] = lj;
            }
            qhi[s][ks] = h8;
            qlo[s][ks] = l8;
        }
    }

    f32x4 oacc[2][8];
    #pragma unroll
    for (int s = 0; s < 2; ++s)
        #pragma unroll
        for (int nt = 0; nt < 8; ++nt)
            oacc[s][nt] = (f32x4){0.f, 0.f, 0.f, 0.f};

    float m_r[2][4], l_r[2][4];
    #pragma unroll
    for (int s = 0; s < 2; ++s)
        #pragma unroll
        for (int reg = 0; reg < 4; ++reg) { m_r[s][reg] = NEGF; l_r[s][reg] = 0.f; }

    const int nkt = 4 * (qblk + 1);

    for (int kt = 0; kt < nkt; ++kt) {
        const int k0 = kt * 32;
        __syncthreads();
        // ---- stage K (hi/lo split) and V (bf16, transposed + swizzled) ----
        #pragma unroll
        for (int it = 0; it < 4; ++it) {
            int idx = tid + 256 * it;      // 0..1023
            int r   = idx >> 5;            // 0..31 (r>>3 == it)
            int c4  = idx & 31;            // float4 within row
            size_t off = inbase + (size_t)(k0 + r) * CEMB + 4 * c4;
            float4 kv = *(const float4*)(K + off);
            float4 vv = *(const float4*)(V + off);
            short4 khi4, klo4;
            split2(kv.x, khi4.x, klo4.x); split2(kv.y, khi4.y, klo4.y);
            split2(kv.z, khi4.z, klo4.z); split2(kv.w, khi4.w, klo4.w);
            *(short4*)&Khi[r][4 * c4] = khi4;
            *(short4*)&Klo[r][4 * c4] = klo4;
            int pos = 8 * (it ^ (c4 & 3)) + (r & 7);
            Vt[4 * c4 + 0][pos] = f2bf(vv.x);
            Vt[4 * c4 + 1][pos] = f2bf(vv.y);
            Vt[4 * c4 + 2][pos] = f2bf(vv.z);
            Vt[4 * c4 + 3][pos] = f2bf(vv.w);
        }
        __syncthreads();

        if (k0 <= q0w + 31) {   // causal: wave has live rows in this K-tile
            // ---- S = Q·K^T via 4-term bf16-split MFMA (exact to accum error) ----
            f32x4 sacc[2][2];
            #pragma unroll
            for (int s = 0; s < 2; ++s)
                #pragma unroll
                for (int nt = 0; nt < 2; ++nt)
                    sacc[s][nt] = (f32x4){0.f, 0.f, 0.f, 0.f};

            __builtin_amdgcn_s_setprio(1);
            #pragma unroll
            for (int ks = 0; ks < 4; ++ks) {
                #pragma unroll
                for (int nt = 0; nt < 2; ++nt) {
                    bf16x8 khf = *(const bf16x8*)&Khi[16 * nt + n][32 * ks + 8 * quad];
                    bf16x8 klf = *(const bf16x8*)&Klo[16 * nt + n][32 * ks + 8 * quad];
                    #pragma unroll
                    for (int s = 0; s < 2; ++s) {
                        sacc[s][nt] = __builtin_amdgcn_mfma_f32_16x16x32_bf16(qhi[s][ks], khf, sacc[s][nt], 0, 0, 0);
                        sacc[s][nt] = __builtin_amdgcn_mfma_f32_16x16x32_bf16(qhi[s][ks], klf, sacc[s][nt], 0, 0, 0);
                        sacc[s][nt] = __builtin_amdgcn_mfma_f32_16x16x32_bf16(qlo[s][ks], khf, sacc[s][nt], 0, 0, 0);
                        sacc[s][nt] = __builtin_amdgcn_mfma_f32_16x16x32_bf16(qlo[s][ks], klf, sacc[s][nt], 0, 0, 0);
                    }
                }
            }
            __builtin_amdgcn_s_setprio(0);

            // ---- floor + fp64 boundary fixup + online softmax, write P ----
            #pragma unroll
            for (int s = 0; s < 2; ++s) {
                float sc[2][4];
                #pragma unroll
                for (int nt = 0; nt < 2; ++nt) {
                    #pragma unroll
                    for (int reg = 0; reg < 4; ++reg) {
                        int qrow = q0w + 16 * s + 4 * quad + reg;
                        int kcol = k0 + 16 * nt + n;
                        if (kcol > qrow) { sc[nt][reg] = NEGF; continue; }
                        float sv = sacc[s][nt][reg] * inv_scale;
                        float f  = floorf(sv);
                        float fr = sv - f;
                        if (fr < WIN || fr > 1.0f - WIN) {
                            // vectorized fp64 re-check: 4 independent chains
                            const float4* qp4 = (const float4*)(Q + inbase + (size_t)qrow * CEMB);
                            const float4* kp4 = (const float4*)(K + inbase + (size_t)kcol * CEMB);
                            double d0 = 0.0, d1 = 0.0, d2 = 0.0, d3 = 0.0;
                            #pragma unroll 2
                            for (int kk = 0; kk < HD / 4; ++kk) {
                                float4 aq = qp4[kk];
                                float4 bk = kp4[kk];
                                d0 += (double)aq.x * bk.x;
                                d1 += (double)aq.y * bk.y;
                                d2 += (double)aq.z * bk.z;
                                d3 += (double)aq.w * bk.w;
                            }
                            f = (float)floor(((d0 + d1) + (d2 + d3)) / dscale);
                        }
                        sc[nt][reg] = f;
                    }
                }
                // scores are floored integers; exp args are ints <= 0.
                // __expf = v_mul + v_exp_f32; exp(-1e30) underflows to 0,
                // which makes the old NEGF guards unnecessary. (mn is always
                // finite: entered tiles have k0 <= q0w <= qrow, so every row
                // has >=1 unmasked column from tile 0 on.)
                float alphaL[4];
                #pragma unroll
                for (int reg = 0; reg < 4; ++reg) {
                    float tm = fmaxf(sc[0][reg], sc[1][reg]);
                    tm = fmaxf(tm, __shfl_xor(tm, 1));
                    tm = fmaxf(tm, __shfl_xor(tm, 2));
                    tm = fmaxf(tm, __shfl_xor(tm, 4));
                    tm = fmaxf(tm, __shfl_xor(tm, 8));
                    float mo = m_r[s][reg];
                    float mn = fmaxf(mo, tm);
                    float al = __expf(mo - mn);
                    float p0 = __expf(sc[0][reg] - mn);
                    float p1 = __expf(sc[1][reg] - mn);
                    float ps = p0 + p1;
                    ps += __shfl_xor(ps, 1);
                    ps += __shfl_xor(ps, 2);
                    ps += __shfl_xor(ps, 4);
                    ps += __shfl_xor(ps, 8);
                    l_r[s][reg] = l_r[s][reg] * al + ps;
                    m_r[s][reg] = mn;
                    alphaL[reg] = al;
                    Ps[wave][16 * s + 4 * quad + reg][n]      = f2bf(p0);
                    Ps[wave][16 * s + 4 * quad + reg][16 + n] = f2bf(p1);
                }
                // T13 defer-rescale: alphas are exp(integer diff) == 1.0f
                // exactly when the running max didn't grow (common case).
                if (!__all(alphaL[0] == 1.0f && alphaL[1] == 1.0f &&
                           alphaL[2] == 1.0f && alphaL[3] == 1.0f)) {
                    #pragma unroll
                    for (int ntv = 0; ntv < 8; ++ntv) {
                        #pragma unroll
                        for (int reg = 0; reg < 4; ++reg)
                            oacc[s][ntv][reg] *= alphaL[reg];
                    }
                }
            }

            // ---- O += P·V: A-frag from Ps, B-frag b128 from swizzled Vt ----
            bf16x8 pfa[2];
            pfa[0] = *(const bf16x8*)&Ps[wave][n][8 * quad];
            pfa[1] = *(const bf16x8*)&Ps[wave][16 + n][8 * quad];
            __builtin_amdgcn_s_setprio(1);
            #pragma unroll
            for (int ntv = 0; ntv < 8; ++ntv) {
                bf16x8 vf = *(const bf16x8*)&Vt[16 * ntv + n][8 * (quad ^ (n >> 2))];
                oacc[0][ntv] = __builtin_amdgcn_mfma_f32_16x16x32_bf16(pfa[0], vf, oacc[0][ntv], 0, 0, 0);
                oacc[1][ntv] = __builtin_amdgcn_mfma_f32_16x16x32_bf16(pfa[1], vf, oacc[1][ntv], 0, 0, 0);
            }
            __builtin_amdgcn_s_setprio(0);
        }
    }

    // ---- normalize + write bf16 merged-head layout [b, t, h*128 + c] ----
    #pragma unroll
    for (int s = 0; s < 2; ++s) {
        #pragma unroll
        for (int reg = 0; reg < 4; ++reg) {
            float inv = 1.0f / l_r[s][reg];
            int qrow = q0w + 16 * s + 4 * quad + reg;
            __hip_bfloat16* op = O + ((size_t)b * TSEQ + qrow) * CEMB + (size_t)h * HD;
            #pragma unroll
            for (int ntv = 0; ntv < 8; ++ntv)
                op[16 * ntv + n] = __float2bfloat16(oacc[s][ntv][reg] * inv);
        }
    }
}

// ---------------- projection: out = X(bf16) @ W^T + bias, MFMA ----------------
// Tile 128x128, K-slab 32. Block 256 = 4 waves in 2x2; wave does 64x64 via
// 4x4 sub-tiles of 16x16x32 (one MFMA consumes the whole slab).
__global__ __launch_bounds__(256)
void proj_mfma(const __hip_bfloat16* __restrict__ X, const float* __restrict__ W,
               const float* __restrict__ bias, float* __restrict__ out)
{
    __shared__ __align__(16) short Xs[128][40];
    __shared__ __align__(16) short Ws[128][40];

    const int tid  = threadIdx.x;
    const int wave = tid >> 6;
    const int lane = tid & 63;
    const int quad = lane >> 4;
    const int n    = lane & 15;
    const int wm   = wave >> 1;
    const int wn   = wave & 1;

    const int m0 = blockIdx.y * 128;
    const int n0 = blockIdx.x * 128;

    f32x4 acc[4][4];
    #pragma unroll
    for (int i = 0; i < 4; ++i)
        #pragma unroll
        for (int j = 0; j < 4; ++j)
            acc[i][j] = (f32x4){0.f, 0.f, 0.f, 0.f};

    for (int k0 = 0; k0 < CEMB; k0 += 32) {
        __syncthreads();
        // X: bf16 direct, 128x32 = 512 16B-chunks
        #pragma unroll
        for (int ii = 0; ii < 2; ++ii) {
            int idx = tid + 256 * ii;          // 0..511
            int row = idx >> 2;                // 0..127
            int c   = idx & 3;                 // 16B group
            *(bf16x8*)&Xs[row][8 * c] =
                *(const bf16x8*)(X + (size_t)(m0 + row) * CEMB + k0 + 8 * c);
        }
        // W: fp32 -> bf16, 128x32 = 1024 float4
        #pragma unroll
        for (int ii = 0; ii < 4; ++ii) {
            int idx = tid + 256 * ii;          // 0..1023
            int row = idx >> 3;                // 0..127
            int c4  = idx & 7;
            float4 wv = *(const float4*)(W + (size_t)(n0 + row) * CEMB + k0 + 4 * c4);
            short4 w4;
            w4.x = f2bf(wv.x); w4.y = f2bf(wv.y); w4.z = f2bf(wv.z); w4.w = f2bf(wv.w);
            *(short4*)&Ws[row][4 * c4] = w4;
        }
        __syncthreads();

        bf16x8 a[4], bb[4];
        #pragma unroll
        for (int i = 0; i < 4; ++i)
            a[i] = *(const bf16x8*)&Xs[64 * wm + 16 * i + n][8 * quad];
        #pragma unroll
        for (int j = 0; j < 4; ++j)
            bb[j] = *(const bf16x8*)&Ws[64 * wn + 16 * j + n][8 * quad];
        #pragma unroll
        for (int i = 0; i < 4; ++i)
            #pragma unroll
            for (int j = 0; j < 4; ++j)
                acc[i][j] = __builtin_amdgcn_mfma_f32_16x16x32_bf16(a[i], bb[j], acc[i][j], 0, 0, 0);
    }

    #pragma unroll
    for (int j = 0; j < 4; ++j) {
        int col = n0 + 64 * wn + 16 * j + n;
        float bj = bias[col];
        #pragma unroll
        for (int i = 0; i < 4; ++i) {
            #pragma unroll
            for (int reg = 0; reg < 4; ++reg) {
                int row = m0 + 64 * wm + 16 * i + 4 * quad + reg;
                out[(size_t)row * CEMB + col] = acc[i][j][reg] + bj;
            }
        }
    }
}

extern "C" void kernel_launch(void* const* d_in, const int* in_sizes, int n_in,
                              void* d_out, int out_size, void* d_ws, size_t ws_size,
                              hipStream_t stream)
{
    // setup_inputs order: v, k, q, W_out, b_out
    const float* v    = (const float*)d_in[0];
    const float* k    = (const float*)d_in[1];
    const float* q    = (const float*)d_in[2];
    const float* W    = (const float*)d_in[3];
    const float* bias = (const float*)d_in[4];

    __hip_bfloat16* attn = (__hip_bfloat16*)d_ws;   // B*T*C bf16 = 32 MiB scratch
    float* out = (float*)d_out;

    attn_mfma<<<dim3(1024), 256, 0, stream>>>(q, k, v, attn);

    dim3 pgrid(CEMB / 128, (BATCH * TSEQ) / 128);   // (16, 64)
    proj_mfma<<<pgrid, 256, 0, stream>>>(attn, W, bias, out);
}